// Round 12
// baseline (121.451 us; speedup 1.0000x reference)
//
#include <hip/hip_runtime.h>

typedef unsigned short u16;
typedef __bf16 bf16x8 __attribute__((ext_vector_type(8)));
typedef float  f32x16 __attribute__((ext_vector_type(16)));

__device__ __forceinline__ u16 f2bf(float f) {
    union { float f; unsigned u; } v; v.f = f;
    return (u16)((v.u + 0x7fffu + ((v.u >> 16) & 1u)) >> 16);
}

#define GLD16(gsrc, ldst) \
    __builtin_amdgcn_global_load_lds( \
        (const __attribute__((address_space(1))) void*)(gsrc), \
        (__attribute__((address_space(3))) void*)(ldst), 16, 0, 0)

// ---------------------------------------------------------------------------
// 1) s_raw[b][c] = w[b] @ mod_w[c] + mod_b[c]
// ---------------------------------------------------------------------------
__global__ __launch_bounds__(256) void lin_kernel(
    const float* __restrict__ w, const float* __restrict__ mod_w,
    const float* __restrict__ mod_b, float* __restrict__ s_raw)
{
    int gw = (blockIdx.x * 256 + threadIdx.x) >> 6;
    int lane = threadIdx.x & 63;
    int b = gw >> 9, c = gw & 511;
    const float* wr = w + b * 512;
    const float* mr = mod_w + (size_t)c * 512;
    float a = 0.f;
#pragma unroll
    for (int i = 0; i < 8; ++i)
        a = fmaf(wr[lane + i * 64], mr[lane + i * 64], a);
    for (int off = 32; off; off >>= 1) a += __shfl_down(a, off);
    if (!lane) s_raw[gw] = a + mod_b[c];
}

// ---------------------------------------------------------------------------
// 2) s_eff = LeakyReLU(LN(s_raw)) * scale
// ---------------------------------------------------------------------------
__global__ __launch_bounds__(512) void norm_kernel(
    const float* __restrict__ s_raw, const float* __restrict__ ln_g,
    const float* __restrict__ ln_b, const float* __restrict__ scale,
    float* __restrict__ s_eff)
{
    int b = blockIdx.x, c = threadIdx.x;
    __shared__ float rs[512], rq[512];
    float s = s_raw[b * 512 + c];
    rs[c] = s; rq[c] = s * s;
    __syncthreads();
    for (int off = 256; off; off >>= 1) {
        if (c < off) { rs[c] += rs[c + off]; rq[c] += rq[c + off]; }
        __syncthreads();
    }
    float mean = rs[0] * (1.f / 512.f);
    float var  = rq[0] * (1.f / 512.f) - mean * mean;
    float sn = (s - mean) * rsqrtf(var + 1e-5f) * ln_g[c] + ln_b[c];
    sn = sn >= 0.f ? sn : 0.2f * sn;
    s_eff[b * 512 + c] = sn * scale[c];
}

// ---------------------------------------------------------------------------
// 3) wsq[co][ci] = sum_p weight^2 ; wbfT[(p*64+cg)*512*8 + co*8 + cj] = bf16(w)
// ---------------------------------------------------------------------------
__global__ __launch_bounds__(256) void wsq_kernel(
    const float* __restrict__ weight, float* __restrict__ wsq, u16* __restrict__ wbfT)
{
    int idx = blockIdx.x * 256 + threadIdx.x;      // co*512+ci
    int co = idx >> 9, ci = idx & 511;
    int cg = ci >> 3, cj = ci & 7;
    const float* wp = weight + (size_t)idx * 9;
    float s = 0.f;
#pragma unroll
    for (int p = 0; p < 9; ++p) {
        float v = wp[p];
        s += v * v;
        wbfT[((size_t)(p * 64 + cg) * 512 + co) * 8 + cj] = f2bf(v);
    }
    wsq[idx] = s;
}

// ---------------------------------------------------------------------------
// 4) xs[b][h][w][c] (NHWC bf16) = bf16(x[b][c][h][w] * s_eff[b][c])
// ---------------------------------------------------------------------------
__global__ __launch_bounds__(256) void xs_kernel(
    const float* __restrict__ x, const float* __restrict__ s_eff,
    u16* __restrict__ xs)
{
    const int bh = blockIdx.x;
    const int b = bh >> 5, h = bh & 31;
    __shared__ float tile[64][33];
    for (int c0 = 0; c0 < 512; c0 += 64) {
        if (c0) __syncthreads();
        for (int idx = threadIdx.x; idx < 2048; idx += 256) {
            int c = idx >> 5, ww = idx & 31;
            tile[c][ww] = x[(((size_t)b * 512 + c0 + c) * 32 + h) * 32 + ww]
                          * s_eff[b * 512 + c0 + c];
        }
        __syncthreads();
        for (int idx = threadIdx.x; idx < 2048; idx += 256) {
            int ww = idx >> 6, c = idx & 63;
            xs[((b * 32 + h) * 32 + ww) * 512 + c0 + c] = f2bf(tile[c][ww]);
        }
    }
}

// ---------------------------------------------------------------------------
// 5) dsc[b][o] = rsqrt(sum_i s_eff[b][i]^2 * wsq[o][i] + 1e-8)
// ---------------------------------------------------------------------------
__global__ __launch_bounds__(256) void dsc_kernel(
    const float* __restrict__ s_eff, const float* __restrict__ wsq,
    float* __restrict__ dsc)
{
    int gw = (blockIdx.x * 256 + threadIdx.x) >> 6;
    int lane = threadIdx.x & 63;
    int b = gw >> 9, co = gw & 511;
    float a = 0.f;
#pragma unroll
    for (int i = 0; i < 8; ++i) {
        int cin = lane + i * 64;
        float se = s_eff[b * 512 + cin];
        a += se * se * wsq[co * 512 + cin];
    }
    for (int off = 32; off; off >>= 1) a += __shfl_down(a, off);
    if (!lane) dsc[gw] = rsqrtf(a + 1e-8f);
}

// ---------------------------------------------------------------------------
// 6) zero page for halo OOB lanes
// ---------------------------------------------------------------------------
__global__ void zfill_kernel(float* p) { p[threadIdx.x] = 0.f; }

// ---------------------------------------------------------------------------
// 7) conv, phase machine with COUNTED vmcnt (T3+T4 proper).
//    Grid 256 = 4 mt (XCD-pinned via bx&7 -> bx&3 const) x 64 8-row strips.
//    512 thr = 8 waves (2 wm x 4 wn), wave 64co x 64px. BM=128, BN=256.
//    48 phases: t = 3r+phi; phase = kernel row (3 taps, 24 MFMA/wave).
//    A: [3 buf][3 pp][4 kc][128 co][16B] 24KB/buf, staged TWO phases ahead
//       (read buf = phi, stage buf = (phi+2)%3, both compile-time).
//    B: [2 buf][4 kc][340 p][16B] 24KB/buf (21.76 used), staged 1 round
//       ahead at phi=1.  kc-major => consecutive-16B reads, 0 conflicts.
//    Ledger (per wave: A=3 gld_lds/phase, B=3 at phi1):
//      phi0: vmcnt(3)   phi1: vmcnt(6) [r15: 0]   phi2: vmcnt(3)
// ---------------------------------------------------------------------------
__global__ __launch_bounds__(512) void conv_kernel(
    const u16* __restrict__ wbfT,  // [576 kflat8][512 co][8]
    const u16* __restrict__ xs,    // [16][32][32][512]
    const float* __restrict__ dsc, // [16][512]
    const u16* __restrict__ zp,    // >=16B zeros
    float* __restrict__ out)       // [16][512][32][32]
{
    __shared__ __align__(16) u16 ldsA[3][12288];   // 3 x 24 KB
    __shared__ __align__(16) u16 ldsB[2][12288];   // 2 x 24 KB

    const int tid  = threadIdx.x;
    const int lane = tid & 63;
    const int wv   = tid >> 6;       // 0..7
    const int wm   = wv >> 2;        // 0..1  M-wave (64 co each)
    const int wn   = wv & 3;         // 0..3  N-wave (2 rows each)
    const int l31  = lane & 31;
    const int kc8  = lane >> 5;

    const int bx = blockIdx.x;       // 256 blocks
    const int mt = bx & 3;           // cout quarter, fixed per XCD (bx&7)
    const int nt = bx >> 2;          // 0..63
    const int b  = nt >> 2;
    const int h0 = (nt & 3) << 3;    // 8 output rows

    const u16* xsb = xs + (size_t)b * (32 * 32 * 512);

    // ---- A staging: 1536 chunks; ch = tid + k*512, k<3 ----
    // ch = pp*512 + kc*128 + co ; LDS dest byte = ch*16 (linear)
    const u16* asrc[3];
#pragma unroll
    for (int k = 0; k < 3; ++k) {
        int ch = tid + k * 512;
        int pp = ch >> 9, kc = (ch >> 7) & 3, co = ch & 127;
        // initial target (r=0, phi=0): pos = pp, kflat8 = pp*64 + kc
        asrc[k] = wbfT + ((size_t)(pp * 64 + kc) * 512 + mt * 128 + co) * 8;
    }
    auto stageA = [&](int buf) {
        char* d = (char*)ldsA[buf] + wv * 1024;
#pragma unroll
        for (int k = 0; k < 3; ++k) GLD16(asrc[k], d + k * 8192);
    };
    auto advA = [&](int dkf) {       // delta in kflat8 units (x4096 u16)
#pragma unroll
        for (int k = 0; k < 3; ++k) asrc[k] += (long)dkf * 4096;
    };

    // ---- B staging: 1536 chunks (1360 valid); ch = tid + k*512, k<3 ----
    // ch = kc*340 + p (ch<1360); LDS dest byte = ch*16 (linear)
    const u16* bsrc[3]; bool binb[3];
#pragma unroll
    for (int k = 0; k < 3; ++k) {
        int ch = tid + k * 512;
        int kc = ch / 340, p = ch % 340;
        int rr = p / 34, cc = p % 34;
        int hh = h0 - 1 + rr, ww = cc - 1;
        binb[k] = (ch < 1360) && ((unsigned)hh < 32u) && ((unsigned)ww < 32u);
        bsrc[k] = xsb + (hh * 32 + ww) * 512 + kc * 8;
    }
    auto stageB = [&](int buf) {
        char* d = (char*)ldsB[buf] + wv * 1024;
#pragma unroll
        for (int k = 0; k < 3; ++k) GLD16(binb[k] ? bsrc[k] : zp, d + k * 8192);
    };

    f32x16 acc[2][2] = {};   // [mf][nf]

    // ---- prologue: A(t=0)->buf0, A(t=1)->buf1, B(r0)->buf0; full drain ----
    stageA(0); advA(192);
    stageA(1); advA(192);    // asrc now at (r0, phi2) = target of t=0's stage
    stageB(0);
    asm volatile("s_waitcnt vmcnt(0)" ::: "memory");
    __builtin_amdgcn_s_barrier();

    for (int r = 0; r < 16; ++r) {
        const char* Bb = (const char*)ldsB[r & 1];
        const bool lastR = (r == 15);

#pragma unroll
        for (int phi = 0; phi < 3; ++phi) {
            const char* Ab = (const char*)ldsA[phi];

            // ---- 24 ds_read frags (consecutive-16B per lane, 0-conflict) ----
            bf16x8 af[3][2][2], bfr[3][2][2];
#pragma unroll
            for (int pp = 0; pp < 3; ++pp)
#pragma unroll
                for (int kk = 0; kk < 2; ++kk) {
                    const int kc = kk * 2 + kc8;
#pragma unroll
                    for (int mf = 0; mf < 2; ++mf) {
                        int co = wm * 64 + mf * 32 + l31;
                        af[pp][mf][kk] = *reinterpret_cast<const bf16x8*>(
                            Ab + (((pp * 4 + kc) * 128 + co) << 4));
                    }
#pragma unroll
                    for (int nf = 0; nf < 2; ++nf) {
                        int p = (wn * 2 + nf + phi) * 34 + l31 + pp;
                        bfr[pp][nf][kk] = *reinterpret_cast<const bf16x8*>(
                            Bb + ((kc * 340 + p) << 4));
                    }
                }

            // ---- stage issues (A: 2 phases ahead; B: next round at phi1) ----
            if (!(lastR && phi >= 1)) {
                stageA((phi + 2) % 3);
                advA(phi == 0 ? -380 : 192);
            }
            if (phi == 1 && !lastR) {
#pragma unroll
                for (int k = 0; k < 3; ++k) bsrc[k] += 32;
                stageB((r + 1) & 1);
            }

            __builtin_amdgcn_s_barrier();
            asm volatile("s_waitcnt lgkmcnt(0)" ::: "memory");
            __builtin_amdgcn_sched_barrier(0);

            __builtin_amdgcn_s_setprio(1);
#pragma unroll
            for (int pp = 0; pp < 3; ++pp)
#pragma unroll
                for (int kk = 0; kk < 2; ++kk) {
                    acc[0][0] = __builtin_amdgcn_mfma_f32_32x32x16_bf16(
                        af[pp][0][kk], bfr[pp][0][kk], acc[0][0], 0, 0, 0);
                    acc[0][1] = __builtin_amdgcn_mfma_f32_32x32x16_bf16(
                        af[pp][0][kk], bfr[pp][1][kk], acc[0][1], 0, 0, 0);
                    acc[1][0] = __builtin_amdgcn_mfma_f32_32x32x16_bf16(
                        af[pp][1][kk], bfr[pp][0][kk], acc[1][0], 0, 0, 0);
                    acc[1][1] = __builtin_amdgcn_mfma_f32_32x32x16_bf16(
                        af[pp][1][kk], bfr[pp][1][kk], acc[1][1], 0, 0, 0);
                }
            __builtin_amdgcn_s_setprio(0);
            __builtin_amdgcn_sched_barrier(0);

            // ---- counted vmcnt ledger + barrier ----
            if (phi == 0) {
                asm volatile("s_waitcnt vmcnt(3)" ::: "memory");
                __builtin_amdgcn_s_barrier();
            } else if (phi == 1) {
                if (!lastR) asm volatile("s_waitcnt vmcnt(6)" ::: "memory");
                else        asm volatile("s_waitcnt vmcnt(0)" ::: "memory");
                __builtin_amdgcn_s_barrier();
            } else {
                if (!lastR) {
                    asm volatile("s_waitcnt vmcnt(3)" ::: "memory");
                    __builtin_amdgcn_s_barrier();
                }
            }
        }
    }

    // ---- epilogue: C/D col=lane&31, row=(q&3)+8*(q>>2)+4*(lane>>5) ----
    const float* db = dsc + b * 512;
#pragma unroll
    for (int mf = 0; mf < 2; ++mf) {
#pragma unroll
        for (int nf = 0; nf < 2; ++nf) {
            const int h = h0 + wn * 2 + nf, w = l31;
#pragma unroll
            for (int q = 0; q < 16; ++q) {
                int row = (q & 3) + 8 * (q >> 2) + 4 * kc8;
                int co  = mt * 128 + wm * 64 + mf * 32 + row;
                out[(((size_t)b * 512 + co) * 32 + h) * 32 + w]
                    = acc[mf][nf][q] * db[co];
            }
        }
    }
}

// ---------------------------------------------------------------------------
extern "C" void kernel_launch(void* const* d_in, const int* in_sizes, int n_in,
                              void* d_out, int out_size, void* d_ws, size_t ws_size,
                              hipStream_t stream) {
    const float* x      = (const float*)d_in[0];
    const float* w      = (const float*)d_in[1];
    const float* mod_w  = (const float*)d_in[2];
    const float* mod_b  = (const float*)d_in[3];
    const float* ln_g   = (const float*)d_in[4];
    const float* ln_b   = (const float*)d_in[5];
    const float* weight = (const float*)d_in[6];
    const float* scale  = (const float*)d_in[7];
    float* out = (float*)d_out;

    char* ws = (char*)d_ws;
    float* s_raw = (float*)(ws);                     // 32 KB, reused as dsc
    float* dsc   = (float*)(ws);
    float* s_eff = (float*)(ws + 32768);             // 32 KB; head reused as zeros page
    float* wsq   = (float*)(ws + 65536);             // 1 MB
    u16*   wbfT  = (u16*)(ws + 65536 + 1048576);     // 4.5 MB
    u16*   xs    = (u16*)(ws + 65536 + 1048576 + 4718592);  // 16.78 MB
    if (ws_size < 22609920u) return;

    lin_kernel <<<2048, 256, 0, stream>>>(w, mod_w, mod_b, s_raw);
    wsq_kernel <<<1024, 256, 0, stream>>>(weight, wsq, wbfT);
    norm_kernel<<<16, 512, 0, stream>>>(s_raw, ln_g, ln_b, scale, s_eff);
    xs_kernel  <<<512, 256, 0, stream>>>(x, s_eff, xs);
    dsc_kernel <<<2048, 256, 0, stream>>>(s_eff, wsq, dsc);
    zfill_kernel<<<1, 1024, 0, stream>>>(s_eff);     // zeros page (s_eff dead now)
    conv_kernel<<<256, 512, 0, stream>>>(wbfT, xs, dsc, (const u16*)s_eff, out);
}

// Round 13
// 121.370 us; speedup vs baseline: 1.0007x; 1.0007x over previous
//
#include <hip/hip_runtime.h>

typedef unsigned short u16;
typedef __bf16 bf16x8 __attribute__((ext_vector_type(8)));
typedef float  f32x16 __attribute__((ext_vector_type(16)));

__device__ __forceinline__ u16 f2bf(float f) {
    union { float f; unsigned u; } v; v.f = f;
    return (u16)((v.u + 0x7fffu + ((v.u >> 16) & 1u)) >> 16);
}

#define GLD16(gsrc, ldst) \
    __builtin_amdgcn_global_load_lds( \
        (const __attribute__((address_space(1))) void*)(gsrc), \
        (__attribute__((address_space(3))) void*)(ldst), 16, 0, 0)

// ---------------------------------------------------------------------------
// 1) s_raw[b][c] = w[b] @ mod_w[c] + mod_b[c]
// ---------------------------------------------------------------------------
__global__ __launch_bounds__(256) void lin_kernel(
    const float* __restrict__ w, const float* __restrict__ mod_w,
    const float* __restrict__ mod_b, float* __restrict__ s_raw)
{
    int gw = (blockIdx.x * 256 + threadIdx.x) >> 6;
    int lane = threadIdx.x & 63;
    int b = gw >> 9, c = gw & 511;
    const float* wr = w + b * 512;
    const float* mr = mod_w + (size_t)c * 512;
    float a = 0.f;
#pragma unroll
    for (int i = 0; i < 8; ++i)
        a = fmaf(wr[lane + i * 64], mr[lane + i * 64], a);
    for (int off = 32; off; off >>= 1) a += __shfl_down(a, off);
    if (!lane) s_raw[gw] = a + mod_b[c];
}

// ---------------------------------------------------------------------------
// 2) s_eff = LeakyReLU(LN(s_raw)) * scale
// ---------------------------------------------------------------------------
__global__ __launch_bounds__(512) void norm_kernel(
    const float* __restrict__ s_raw, const float* __restrict__ ln_g,
    const float* __restrict__ ln_b, const float* __restrict__ scale,
    float* __restrict__ s_eff)
{
    int b = blockIdx.x, c = threadIdx.x;
    __shared__ float rs[512], rq[512];
    float s = s_raw[b * 512 + c];
    rs[c] = s; rq[c] = s * s;
    __syncthreads();
    for (int off = 256; off; off >>= 1) {
        if (c < off) { rs[c] += rs[c + off]; rq[c] += rq[c + off]; }
        __syncthreads();
    }
    float mean = rs[0] * (1.f / 512.f);
    float var  = rq[0] * (1.f / 512.f) - mean * mean;
    float sn = (s - mean) * rsqrtf(var + 1e-5f) * ln_g[c] + ln_b[c];
    sn = sn >= 0.f ? sn : 0.2f * sn;
    s_eff[b * 512 + c] = sn * scale[c];
}

// ---------------------------------------------------------------------------
// 3) wsq[co][ci] = sum_p weight^2 ; wbfT[(p*64+cg)*512*8 + co*8 + cj] = bf16(w)
// ---------------------------------------------------------------------------
__global__ __launch_bounds__(256) void wsq_kernel(
    const float* __restrict__ weight, float* __restrict__ wsq, u16* __restrict__ wbfT)
{
    int idx = blockIdx.x * 256 + threadIdx.x;      // co*512+ci
    int co = idx >> 9, ci = idx & 511;
    int cg = ci >> 3, cj = ci & 7;
    const float* wp = weight + (size_t)idx * 9;
    float s = 0.f;
#pragma unroll
    for (int p = 0; p < 9; ++p) {
        float v = wp[p];
        s += v * v;
        wbfT[((size_t)(p * 64 + cg) * 512 + co) * 8 + cj] = f2bf(v);
    }
    wsq[idx] = s;
}

// ---------------------------------------------------------------------------
// 4) xs[b][h][w][c] (NHWC bf16) = bf16(x[b][c][h][w] * s_eff[b][c])
// ---------------------------------------------------------------------------
__global__ __launch_bounds__(256) void xs_kernel(
    const float* __restrict__ x, const float* __restrict__ s_eff,
    u16* __restrict__ xs)
{
    const int bh = blockIdx.x;
    const int b = bh >> 5, h = bh & 31;
    __shared__ float tile[64][33];
    for (int c0 = 0; c0 < 512; c0 += 64) {
        if (c0) __syncthreads();
        for (int idx = threadIdx.x; idx < 2048; idx += 256) {
            int c = idx >> 5, ww = idx & 31;
            tile[c][ww] = x[(((size_t)b * 512 + c0 + c) * 32 + h) * 32 + ww]
                          * s_eff[b * 512 + c0 + c];
        }
        __syncthreads();
        for (int idx = threadIdx.x; idx < 2048; idx += 256) {
            int ww = idx >> 6, c = idx & 63;
            xs[((b * 32 + h) * 32 + ww) * 512 + c0 + c] = f2bf(tile[c][ww]);
        }
    }
}

// ---------------------------------------------------------------------------
// 5) dsc[b][o] = rsqrt(sum_i s_eff[b][i]^2 * wsq[o][i] + 1e-8)
// ---------------------------------------------------------------------------
__global__ __launch_bounds__(256) void dsc_kernel(
    const float* __restrict__ s_eff, const float* __restrict__ wsq,
    float* __restrict__ dsc)
{
    int gw = (blockIdx.x * 256 + threadIdx.x) >> 6;
    int lane = threadIdx.x & 63;
    int b = gw >> 9, co = gw & 511;
    float a = 0.f;
#pragma unroll
    for (int i = 0; i < 8; ++i) {
        int cin = lane + i * 64;
        float se = s_eff[b * 512 + cin];
        a += se * se * wsq[co * 512 + cin];
    }
    for (int off = 32; off; off >>= 1) a += __shfl_down(a, off);
    if (!lane) dsc[gw] = rsqrtf(a + 1e-8f);
}

// ---------------------------------------------------------------------------
// 6) zero page for halo OOB lanes
// ---------------------------------------------------------------------------
__global__ void zfill_kernel(float* p) { p[threadIdx.x] = 0.f; }

// ---------------------------------------------------------------------------
// 7) conv, R11 phase machine WITHOUT forced serialization: no lgkmcnt(0),
//    no sched_barrier, no setprio; ONE __syncthreads per phase. The compiler
//    interleaves the 24 ds_reads with the 24 MFMAs (counted lgkmcnt), so the
//    LDS pipe (~2300 cyc/phase/CU) overlaps the MFMA pipe (~1536 cyc/SIMD).
//    Grid 256 = 2 mt (XCD-parity) x 128 4-row strips. 512 thr = 8 waves
//    (4 wm x 2 wn), wave 64co x 64px, BM=256, BN=128.
//    A: [2 buf][3 pp][4 kc][256 co][16B] 48KB/buf, gld_lds staged one phase
//       ahead (issued at TOP of phase -> full phase to land).
//    B: [2 buf][4 kc][204 p][16B] 16KB/buf, staged one round ahead at phi=1.
//    kc-major => consecutive-16B frag reads, 0 bank conflicts (R11-verified).
// ---------------------------------------------------------------------------
__global__ __launch_bounds__(512) void conv_kernel(
    const u16* __restrict__ wbfT,  // [576 kflat8][512 co][8]
    const u16* __restrict__ xs,    // [16][32][32][512]
    const float* __restrict__ dsc, // [16][512]
    const u16* __restrict__ zp,    // >=16B zeros
    float* __restrict__ out)       // [16][512][32][32]
{
    __shared__ __align__(16) u16 ldsA[2][24576];   // 2 x 48 KB
    __shared__ __align__(16) u16 ldsB[2][8192];    // 2 x 16 KB (13056 + pad)

    const int tid  = threadIdx.x;
    const int lane = tid & 63;
    const int wv   = tid >> 6;       // 0..7
    const int wm   = wv >> 1;        // 0..3  M-wave (64 co each)
    const int wn   = wv & 1;         // 0..1  N-wave (64 px each)
    const int l31  = lane & 31;
    const int kc8  = lane >> 5;

    const int bx = blockIdx.x;       // 256 blocks
    const int mt = bx & 1;           // XCD-parity-pinned cout half
    const int nt = bx >> 1;          // 0..127
    const int b  = nt >> 3;
    const int h0 = (nt & 7) << 2;    // 4 output rows

    const u16* xsb = xs + (size_t)b * (32 * 32 * 512);

    // ---- A staging: 3072 chunks; ch = tid + k*512, k<6 ----
    // ch = pp*1024 + kc*256 + co ; LDS dest = ch*16 (linear)
    const u16* asrc[6];
#pragma unroll
    for (int k = 0; k < 6; ++k) {
        int ch = tid + k * 512;
        int pp = ch >> 10, kc = (ch >> 8) & 3, co = ch & 255;
        // initial staged target: (r=0, phi=0) -> pos = pp, kflat8 = pp*64+kc
        asrc[k] = wbfT + ((size_t)(pp * 64 + kc) * 512 + mt * 256 + co) * 8;
    }
    auto stageA = [&](int buf) {
        char* d = (char*)ldsA[buf] + wv * 1024;
#pragma unroll
        for (int k = 0; k < 6; ++k) GLD16(asrc[k], d + k * 8192);
    };
    auto advA = [&](int dkf) {       // delta in kflat8 units (x4096 u16)
#pragma unroll
        for (int k = 0; k < 6; ++k) asrc[k] += (long)dkf * 4096;
    };

    // ---- B staging: 816 chunks (+pad to 1024); ch = tid + k*512, k<2 ----
    // ch = kc*204 + p (ch<816); LDS dest = ch*16 (linear)
    const u16* bsrc[2]; bool binb[2];
#pragma unroll
    for (int k = 0; k < 2; ++k) {
        int ch = tid + k * 512;
        int kc = ch / 204, p = ch % 204;
        int rr = p / 34, cc = p % 34;
        int hh = h0 - 1 + rr, ww = cc - 1;
        binb[k] = (ch < 816) && ((unsigned)hh < 32u) && ((unsigned)ww < 32u);
        bsrc[k] = xsb + (hh * 32 + ww) * 512 + kc * 8;
    }
    auto stageB = [&](int buf) {
        char* d = (char*)ldsB[buf] + wv * 1024;
        GLD16(binb[0] ? bsrc[0] : zp, d);
        GLD16(binb[1] ? bsrc[1] : zp, d + 8192);
    };

    f32x16 acc[2][2] = {};

    // ---- prologue: A(t=0)->buf0, B(r0)->buf0; full drain via syncthreads ----
    stageA(0);
    advA(192);                       // now points at (r0, phi1)
    stageB(0);
    __syncthreads();                 // vmcnt(0) drain: buf0 + B buf0 resident

    int pidx = 0;
    for (int r = 0; r < 16; ++r) {
        const char* Bb = (const char*)ldsB[r & 1];
        const bool lastR = (r == 15);

#pragma unroll
        for (int phi = 0; phi < 3; ++phi) {
            const int abuf = pidx & 1;
            const char* Ab = (const char*)ldsA[abuf];
            const bool lastPhase = lastR && (phi == 2);

            // ---- stage issues FIRST (full phase to land under compute) ----
            if (!lastPhase) {
                stageA(abuf ^ 1);
                advA(phi == 1 ? -380 : 192);
            }
            if (phi == 1 && !lastR) {
#pragma unroll
                for (int k = 0; k < 2; ++k) bsrc[k] += 32;   // next 32-cin grp
                stageB((r + 1) & 1);
            }

            // ---- 24 ds_read frags + 24 MFMA: compiler-scheduled overlap ----
            bf16x8 af[3][2][2], bfr[3][2][2];
#pragma unroll
            for (int pp = 0; pp < 3; ++pp)
#pragma unroll
                for (int kk = 0; kk < 2; ++kk) {
                    const int kc = kk * 2 + kc8;
#pragma unroll
                    for (int mf = 0; mf < 2; ++mf) {
                        int co = wm * 64 + mf * 32 + l31;
                        af[pp][mf][kk] = *reinterpret_cast<const bf16x8*>(
                            Ab + (((pp * 4 + kc) * 256 + co) << 4));
                    }
#pragma unroll
                    for (int nf = 0; nf < 2; ++nf) {
                        int p = (wn * 2 + nf + phi) * 34 + l31 + pp;
                        bfr[pp][nf][kk] = *reinterpret_cast<const bf16x8*>(
                            Bb + ((kc * 204 + p) << 4));
                    }
                }

#pragma unroll
            for (int pp = 0; pp < 3; ++pp)
#pragma unroll
                for (int kk = 0; kk < 2; ++kk) {
                    acc[0][0] = __builtin_amdgcn_mfma_f32_32x32x16_bf16(
                        af[pp][0][kk], bfr[pp][0][kk], acc[0][0], 0, 0, 0);
                    acc[0][1] = __builtin_amdgcn_mfma_f32_32x32x16_bf16(
                        af[pp][0][kk], bfr[pp][1][kk], acc[0][1], 0, 0, 0);
                    acc[1][0] = __builtin_amdgcn_mfma_f32_32x32x16_bf16(
                        af[pp][1][kk], bfr[pp][0][kk], acc[1][0], 0, 0, 0);
                    acc[1][1] = __builtin_amdgcn_mfma_f32_32x32x16_bf16(
                        af[pp][1][kk], bfr[pp][1][kk], acc[1][1], 0, 0, 0);
                }

            // ---- single phase barrier (drains are quiescent by now) ----
            if (!lastPhase) __syncthreads();
            ++pidx;
        }
    }

    // ---- epilogue: C/D col=lane&31, row=(q&3)+8*(q>>2)+4*(lane>>5) ----
    const float* db = dsc + b * 512;
#pragma unroll
    for (int mf = 0; mf < 2; ++mf) {
#pragma unroll
        for (int nf = 0; nf < 2; ++nf) {
            const int h = h0 + wn * 2 + nf, w = l31;
#pragma unroll
            for (int q = 0; q < 16; ++q) {
                int row = (q & 3) + 8 * (q >> 2) + 4 * kc8;
                int co  = mt * 256 + wm * 64 + mf * 32 + row;
                out[(((size_t)b * 512 + co) * 32 + h) * 32 + w]
                    = acc[mf][nf][q] * db[co];
            }
        }
    }
}

// ---------------------------------------------------------------------------
extern "C" void kernel_launch(void* const* d_in, const int* in_sizes, int n_in,
                              void* d_out, int out_size, void* d_ws, size_t ws_size,
                              hipStream_t stream) {
    const float* x      = (const float*)d_in[0];
    const float* w      = (const float*)d_in[1];
    const float* mod_w  = (const float*)d_in[2];
    const float* mod_b  = (const float*)d_in[3];
    const float* ln_g   = (const float*)d_in[4];
    const float* ln_b   = (const float*)d_in[5];
    const float* weight = (const float*)d_in[6];
    const float* scale  = (const float*)d_in[7];
    float* out = (float*)d_out;

    char* ws = (char*)d_ws;
    float* s_raw = (float*)(ws);                     // 32 KB, reused as dsc
    float* dsc   = (float*)(ws);
    float* s_eff = (float*)(ws + 32768);             // 32 KB; head reused as zeros page
    float* wsq   = (float*)(ws + 65536);             // 1 MB
    u16*   wbfT  = (u16*)(ws + 65536 + 1048576);     // 4.5 MB
    u16*   xs    = (u16*)(ws + 65536 + 1048576 + 4718592);  // 16.78 MB
    if (ws_size < 22609920u) return;

    lin_kernel <<<2048, 256, 0, stream>>>(w, mod_w, mod_b, s_raw);
    wsq_kernel <<<1024, 256, 0, stream>>>(weight, wsq, wbfT);
    norm_kernel<<<16, 512, 0, stream>>>(s_raw, ln_g, ln_b, scale, s_eff);
    xs_kernel  <<<512, 256, 0, stream>>>(x, s_eff, xs);
    dsc_kernel <<<2048, 256, 0, stream>>>(s_eff, wsq, dsc);
    zfill_kernel<<<1, 1024, 0, stream>>>(s_eff);     // zeros page (s_eff dead now)
    conv_kernel<<<256, 512, 0, stream>>>(wbfT, xs, dsc, (const u16*)s_eff, out);
}